// Round 7
// baseline (292.415 us; speedup 1.0000x reference)
//
#include <hip/hip_runtime.h>

#define NN 20000
#define EE 320000
#define NPB 8
#define NBLK 2500        // NN/NPB
#define CAP 64           // slab slots per node (in-degree ~ Poisson(16))
#define LCAP 80          // LDS per-node edge capacity (CAP + overflow slack)
#define OVCAP 8192
#define PROW 104         // padded pacc row (floats): 16B-aligned, breaks 32-bank stride

// consts layout (float offsets)
#define WZ_O 0
#define BZ_O 512
#define WH_O 576
#define BH_O 1088
#define OW_O 1152
#define OB_O 1920
#define PR_O 1932
#define NCONST 1944

__device__ __forceinline__ float b2f(unsigned short h) {
  union { unsigned int u; float f; } v; v.u = ((unsigned int)h) << 16; return v.f;
}
__device__ __forceinline__ unsigned short f2b(float f) {
  union { unsigned int u; float f; } v; v.f = f;
  unsigned int u = v.u;
  unsigned int r = (u + 0x7fffu + ((u >> 16) & 1u)) >> 16;  // RNE
  return (unsigned short)r;
}
__device__ __forceinline__ float ldw(const void* p, int i, int isbf) {
  return isbf ? b2f(((const unsigned short*)p)[i]) : ((const float*)p)[i];
}
__device__ __forceinline__ void upk(unsigned int w, float& x0, float& x1) {
  union { unsigned int u; float f; } lo, hi;
  lo.u = w << 16; hi.u = w & 0xffff0000u;
  x0 = lo.f; x1 = hi.f;
}
__device__ __forceinline__ float degf(unsigned long long dc) {
  return (float)(unsigned int)dc * (1.0f / 1048576.0f);
}

// 1) init: zero degcnt + ovf_cnt; block 0: dtype detect + fused-weight prep
__global__ void k_init(const unsigned int* __restrict__ ei_w,
                       const unsigned int* __restrict__ ea_w,
                       int* __restrict__ flags,
                       unsigned long long* __restrict__ degcnt,
                       int* __restrict__ ovf_cnt,
                       float* __restrict__ consts,
                       const void* czw, const void* czb,
                       const void* chw, const void* chb,
                       const void* lzw, const void* lzb,
                       const void* lhw, const void* lhb,
                       const void* att, const void* ow, const void* ob) {
  int tid = threadIdx.x;
  int i = blockIdx.x * 256 + tid;
  if (i < NN) degcnt[i] = 0ull;
  if (blockIdx.x == 1 && tid == 0) *ovf_cnt = 0;
  if (blockIdx.x != 0) return;

  __shared__ int sfl[2];
  if (tid < 64) {
    // edge_attr in (0,1): packed-bf16 words have sign bits 15/31 == 0; f32 words random bit15
    unsigned long long b1 = __ballot((ea_w[tid] >> 15) & 1u);
    // edge_index < 20000: int64 arrays have all odd 32-bit words == 0
    unsigned long long b2 = __ballot(ei_w[2 * tid + 1] != 0u);
    if (tid == 0) {
      int f0 = (b1 == 0ull) ? 1 : 0;   // 1 = floats are bf16
      int f1 = (b2 == 0ull) ? 1 : 0;   // 1 = indices are int64
      flags[0] = f0; flags[1] = f1; sfl[0] = f0; sfl[1] = f1;
    }
  }
  __syncthreads();
  int isbf = sfl[0];

  // fused gate weights: Wz = conv_z_w @ lin_z_w[:64], Wh = conv_h_w @ lin_h_w[:64]
  for (int idx = tid; idx < 512; idx += 256) {
    int f = idx >> 6, k = idx & 63;
    float sz = 0.f, sh = 0.f;
    for (int h = 0; h < 64; ++h) {
      sz += ldw(czw, f * 64 + h, isbf) * ldw(lzw, h * 64 + k, isbf);
      sh += ldw(chw, f * 64 + h, isbf) * ldw(lhw, h * 64 + k, isbf);
    }
    consts[WZ_O + idx] = sz; consts[WH_O + idx] = sh;
  }
  for (int idx = tid; idx < 64; idx += 256) {
    float sz = ldw(lzb, idx, isbf), sh = ldw(lhb, idx, isbf);
    for (int h = 0; h < 64; ++h) {
      sz += ldw(czb, h, isbf) * ldw(lzw, h * 64 + idx, isbf);
      sh += ldw(chb, h, isbf) * ldw(lhw, h * 64 + idx, isbf);
    }
    consts[BZ_O + idx] = sz; consts[BH_O + idx] = sh;
  }
  for (int idx = tid; idx < 768; idx += 256) consts[OW_O + idx] = ldw(ow, idx, isbf);
  if (tid < 12) consts[OB_O + tid] = ldw(ob, tid, isbf);
  if (tid == 0) {
    float a[12]; float m = -1e30f;
    for (int p = 0; p < 12; ++p) { a[p] = ldw(att, p, isbf); m = fmaxf(m, a[p]); }
    float ssum = 0.f;
    for (int p = 0; p < 12; ++p) { a[p] = __expf(a[p] - m); ssum += a[p]; }
    for (int p = 0; p < 12; ++p) consts[PR_O + p] = a[p] / ssum;
  }
}

// 2) single-pass adjacency build: one packed 64-bit atomic per edge gives BOTH the
//    slot index (count, hi32) and the weighted-degree accumulation (fixed point, lo32).
__global__ void k_append(const void* __restrict__ ei, const void* __restrict__ ea,
                         const int* __restrict__ flags,
                         unsigned long long* __restrict__ degcnt,
                         unsigned int* __restrict__ slab,
                         int* __restrict__ ovf_cnt, int* __restrict__ ovf_dst,
                         unsigned int* __restrict__ ovf_pack) {
  int isbf = flags[0], is64 = flags[1];
  int e = blockIdx.x * blockDim.x + threadIdx.x;
  if (e >= EE) return;
  int r, c;
  if (is64) {
    r = (int)((const unsigned int*)ei)[2 * e];
    c = (int)((const unsigned int*)ei)[2 * (EE + e)];
  } else {
    r = ((const int*)ei)[e];
    c = ((const int*)ei)[EE + e];
  }
  unsigned short wb;
  float w;
  if (isbf) { wb = ((const unsigned short*)ea)[e]; w = b2f(wb); }
  else      { w = ((const float*)ea)[e]; wb = f2b(w); }
  unsigned long long pk = (1ull << 32) |
      (unsigned long long)(unsigned int)__float2int_rn(w * 1048576.0f);
  unsigned long long old = atomicAdd(&degcnt[c], pk);
  int pos = (int)(old >> 32);
  unsigned int packed = ((unsigned int)wb << 16) | (unsigned int)r;
  if (pos < CAP) {
    slab[c * CAP + pos] = packed;
  } else {
    int oi = atomicAdd(ovf_cnt, 1);
    if (oi < OVCAP) { ovf_dst[oi] = c; ovf_pack[oi] = packed; }
  }
}

// 3) fused per-(batch, node-group) pipeline. Block handles ONE batch's slice of NPB
//    nodes; batch-major block ordering keeps the per-XCD gather working set at
//    ~3.84 MB (one batch slice) -> L2-resident. 16 edge-subgroups x 12 threads.
__global__ void __launch_bounds__(192) k_node(
    const void* __restrict__ x,
    const unsigned long long* __restrict__ degcnt,
    const unsigned int* __restrict__ slab,
    const int* __restrict__ ovf_cnt, const int* __restrict__ ovf_dst,
    const unsigned int* __restrict__ ovf_pack,
    const float* __restrict__ consts, const int* __restrict__ flags,
    void* __restrict__ out) {
  __shared__ __align__(16) float sow[792];           // OW(768) OB(12) PR(12)
  __shared__ __align__(16) float pacc[16 * PROW];    // [sub][96 padded]
  __shared__ __align__(16) float accT[96];           // [p][f]
  __shared__ __align__(16) float hpart[192];         // [g3][k]
  __shared__ int   sedge[NPB * LCAP];                // src*96 (elem offset in slice)
  __shared__ float vedge[NPB * LCAP];                // w * dinv[src]
  __shared__ int   scnt[NPB];
  __shared__ float sdn[NPB];

  const int tid  = threadIdx.x;
  const int isbf = flags[0];
  const int bb   = blockIdx.x / NBLK;                // batch (batch-major order!)
  const int n0   = (blockIdx.x % NBLK) * NPB;

  for (int i = tid; i < 792; i += 192) sow[i] = consts[OW_O + i];

  const int sub = tid / 12;     // edge subgroup 0..15
  const int q   = tid % 12;     // payload elems 8q..8q+7 of the 96-elem [f][p] slice
  const int k   = tid & 63;     // hidden index
  const int g3  = tid / 64;     // p-group 0..2

  const long xbase = (long)bb * (NN * 96) + 8 * q;   // + s*96 -> elem in x[b][s][f][p]

  float wz[8], wh[8];
#pragma unroll
  for (int f = 0; f < 8; ++f) {
    wz[f] = consts[WZ_O + f * 64 + k];
    wh[f] = consts[WH_O + f * 64 + k];
  }
  const float bz = consts[BZ_O + k], bh = consts[BH_O + k];

  if (tid < NPB) {
    unsigned long long dc = degcnt[n0 + tid];
    int cnt = (int)(dc >> 32);
    scnt[tid] = cnt < CAP ? cnt : CAP;
    sdn[tid] = rsqrtf(degf(dc) + 1.0f);
  }
  __syncthreads();

  // stage all NPB nodes' edges (reads degcnt directly to avoid scnt race)
  for (int i = tid; i < NPB * CAP; i += 192) {
    int ni = i >> 6, slot = i & (CAP - 1);
    int cnt = (int)(degcnt[n0 + ni] >> 32);
    if (cnt > CAP) cnt = CAP;
    if (slot < cnt) {
      unsigned int pk = slab[(n0 + ni) * CAP + slot];
      int s = (int)(pk & 0xffffu);
      float w = b2f((unsigned short)(pk >> 16));
      sedge[ni * LCAP + slot] = s * 96;
      vedge[ni * LCAP + slot] = w * rsqrtf(degf(degcnt[s]) + 1.0f);
    }
  }
  {
    int ov = ovf_cnt[0];                 // expected 0
    if (ov > 0) {
      if (ov > OVCAP) ov = OVCAP;
      for (int i = tid; i < ov; i += 192) {
        unsigned int dd = (unsigned int)(ovf_dst[i] - n0);
        if (dd < NPB) {
          int idx = atomicAdd(&scnt[dd], 1);
          if (idx < LCAP) {
            unsigned int pk = ovf_pack[i];
            int s = (int)(pk & 0xffffu);
            float w = b2f((unsigned short)(pk >> 16));
            sedge[dd * LCAP + idx] = s * 96;
            vedge[dd * LCAP + idx] = w * rsqrtf(degf(degcnt[s]) + 1.0f);
          }
        }
      }
    }
  }
  __syncthreads();

  for (int ni = 0; ni < NPB; ++ni) {
    const int n = n0 + ni;
    int m = scnt[ni]; if (m > LCAP) m = LCAP;
    const float dn = sdn[ni];
    float a[8];
#pragma unroll
    for (int t = 0; t < 8; ++t) a[t] = 0.f;

    if (isbf) {
      const unsigned short* xb = (const unsigned short*)x;
      for (int j = sub; j < m; j += 16) {
        int soff = sedge[ni * LCAP + j];
        float v = vedge[ni * LCAP + j];
        uint4 u = *(const uint4*)(xb + xbase + soff);
        float x0, x1;
        upk(u.x, x0, x1); a[0] += v * x0; a[1] += v * x1;
        upk(u.y, x0, x1); a[2] += v * x0; a[3] += v * x1;
        upk(u.z, x0, x1); a[4] += v * x0; a[5] += v * x1;
        upk(u.w, x0, x1); a[6] += v * x0; a[7] += v * x1;
      }
      if (sub == 0) {      // self loop (w=1): outer dn -> dn^2 * x[n]
        uint4 u = *(const uint4*)(xb + xbase + (long)n * 96);
        float x0, x1;
        upk(u.x, x0, x1); a[0] += dn * x0; a[1] += dn * x1;
        upk(u.y, x0, x1); a[2] += dn * x0; a[3] += dn * x1;
        upk(u.z, x0, x1); a[4] += dn * x0; a[5] += dn * x1;
        upk(u.w, x0, x1); a[6] += dn * x0; a[7] += dn * x1;
      }
    } else {
      const float* xf = (const float*)x;
      for (int j = sub; j < m; j += 16) {
        int soff = sedge[ni * LCAP + j];
        float v = vedge[ni * LCAP + j];
        const float4* px = (const float4*)(xf + xbase + soff);
        float4 u0 = px[0], u1 = px[1];
        a[0] += v * u0.x; a[1] += v * u0.y; a[2] += v * u0.z; a[3] += v * u0.w;
        a[4] += v * u1.x; a[5] += v * u1.y; a[6] += v * u1.z; a[7] += v * u1.w;
      }
      if (sub == 0) {
        const float4* px = (const float4*)(xf + xbase + (long)n * 96);
        float4 u0 = px[0], u1 = px[1];
        a[0] += dn * u0.x; a[1] += dn * u0.y; a[2] += dn * u0.z; a[3] += dn * u0.w;
        a[4] += dn * u1.x; a[5] += dn * u1.y; a[6] += dn * u1.z; a[7] += dn * u1.w;
      }
    }
    {
      float4* pg = (float4*)&pacc[sub * PROW + 8 * q];
      pg[0] = make_float4(a[0], a[1], a[2], a[3]);
      pg[1] = make_float4(a[4], a[5], a[6], a[7]);
    }
    __syncthreads();                                  // B1: pacc ready
    if (tid < 96) {                                   // combine + transpose -> accT[p][f]
      int p = tid >> 3, f = tid & 7;
      int src = f * 12 + p;
      float s0 = 0.f;
#pragma unroll
      for (int s = 0; s < 16; ++s) s0 += pacc[s * PROW + src];
      accT[tid] = dn * s0;
    }
    __syncthreads();                                  // B2: accT ready

    // gates: thread (g3, k) handles p in {g3, g3+3, g3+6, g3+9}, batch bb
    float hb = 0.f;
#pragma unroll
    for (int pi = 0; pi < 4; ++pi) {
      int p = g3 + 3 * pi;
      float pr = sow[780 + p];
      const float4* A = (const float4*)&accT[p * 8];
      float4 A0 = A[0], A1 = A[1];
      float za = bz + A0.x * wz[0] + A0.y * wz[1] + A0.z * wz[2] + A0.w * wz[3]
                    + A1.x * wz[4] + A1.y * wz[5] + A1.z * wz[6] + A1.w * wz[7];
      float ta = bh + A0.x * wh[0] + A0.y * wh[1] + A0.z * wh[2] + A0.w * wh[3]
                    + A1.x * wh[4] + A1.y * wh[5] + A1.z * wh[6] + A1.w * wh[7];
      // (1 - sigmoid(za)) * tanh(ta) = (eh-1) / ((1+ea)(1+eh)), ea=e^za, eh=e^{2ta}
      float ea = __expf(za);
      float eh = __expf(2.0f * fminf(ta, 40.0f));
      hb += pr * (eh - 1.0f) * __builtin_amdgcn_rcpf((1.0f + ea) * (1.0f + eh));
    }
    hpart[g3 * 64 + k] = hb;
    __syncthreads();                                  // B3: hpart ready

    // out projection: thread t<96: p = t>>3, k-slice kq = t&7 (8 k's); shuffle-reduce 8 lanes
    if (tid < 96) {
      int p = tid >> 3, kq = tid & 7;
      float o = 0.f;
#pragma unroll
      for (int j = 0; j < 8; ++j) {
        int kk = kq * 8 + j;
        float h = fmaxf(hpart[kk] + hpart[64 + kk] + hpart[128 + kk], 0.f);
        o += h * sow[kk * 12 + p];
      }
      o += __shfl_xor(o, 1);
      o += __shfl_xor(o, 2);
      o += __shfl_xor(o, 4);
      if (kq == 0) {
        float oo = o + sow[768 + p];
        int oi = (bb * NN + n) * 12 + p;
        if (isbf) ((unsigned short*)out)[oi] = f2b(oo);
        else      ((float*)out)[oi] = oo;
      }
    }
    // next node's pacc stores come after B3 (combine readers done at B2) -> safe
  }
}

extern "C" void kernel_launch(void* const* d_in, const int* in_sizes, int n_in,
                              void* d_out, int out_size, void* d_ws, size_t ws_size,
                              hipStream_t stream) {
  const void* x   = d_in[0];
  const void* ei  = d_in[1];
  const void* ea  = d_in[2];
  const void* czw = d_in[3];
  const void* czb = d_in[4];
  // d_in[5], d_in[6]: conv_r_* — dead (H0 = 0)
  const void* chw = d_in[7];
  const void* chb = d_in[8];
  const void* lzw = d_in[9];
  const void* lzb = d_in[10];
  // d_in[11], d_in[12]: lin_r_* — dead
  const void* lhw = d_in[13];
  const void* lhb = d_in[14];
  const void* att = d_in[15];
  const void* ow  = d_in[16];
  const void* ob  = d_in[17];

  // workspace ~5.4 MB
  char* ws = (char*)d_ws;
  int*   flags   = (int*)  (ws + 0);
  float* consts  = (float*)(ws + 256);          // 1944 f32 -> ends 8032
  unsigned long long* degcnt = (unsigned long long*)(ws + 8192);   // 160000 -> 168192
  int*   ovf_cnt = (int*)  (ws + 168192);
  int*   ovf_dst = (int*)  (ws + 168448);       // 32768 -> 201216
  unsigned int* ovf_pack = (unsigned int*)(ws + 201216);  // 32768 -> 233984
  unsigned int* slab     = (unsigned int*)(ws + 240000);  // 5,120,000 -> 5,360,000

  k_init<<<dim3(79), dim3(256), 0, stream>>>((const unsigned int*)ei,
                                             (const unsigned int*)ea, flags, degcnt,
                                             ovf_cnt, consts, czw, czb, chw, chb,
                                             lzw, lzb, lhw, lhb, att, ow, ob);
  k_append<<<dim3(1250), dim3(256), 0, stream>>>(ei, ea, flags, degcnt, slab,
                                                 ovf_cnt, ovf_dst, ovf_pack);
  k_node<<<dim3(4 * NBLK), dim3(192), 0, stream>>>(x, degcnt, slab, ovf_cnt, ovf_dst,
                                                   ovf_pack, consts, flags, d_out);
}

// Round 8
// 240.445 us; speedup vs baseline: 1.2161x; 1.2161x over previous
//
#include <hip/hip_runtime.h>

#define NN 20000
#define EE 320000
#define CAP 64           // slab slots per node (in-degree ~ Poisson(16))
#define SVC 72           // per-wave edge capacity (CAP + ovf slack + self)
#define OVCAP 8192

// consts layout (float offsets)
#define WZ_O 0
#define BZ_O 512
#define WH_O 576
#define BH_O 1088
#define OWT_O 1152       // transposed+padded out weights: [p][68] (k<64 valid)
#define OB_O 1968
#define PR_O 1980
#define NCONST 1992

__device__ __forceinline__ float b2f(unsigned short h) {
  union { unsigned int u; float f; } v; v.u = ((unsigned int)h) << 16; return v.f;
}
__device__ __forceinline__ unsigned short f2b(float f) {
  union { unsigned int u; float f; } v; v.f = f;
  unsigned int u = v.u;
  unsigned int r = (u + 0x7fffu + ((u >> 16) & 1u)) >> 16;  // RNE
  return (unsigned short)r;
}
__device__ __forceinline__ float ldw(const void* p, int i, int isbf) {
  return isbf ? b2f(((const unsigned short*)p)[i]) : ((const float*)p)[i];
}
__device__ __forceinline__ void upk(unsigned int w, float& x0, float& x1) {
  union { unsigned int u; float f; } lo, hi;
  lo.u = w << 16; hi.u = w & 0xffff0000u;
  x0 = lo.f; x1 = hi.f;
}
__device__ __forceinline__ float degf(unsigned long long dc) {
  return (float)(unsigned int)dc * (1.0f / 1048576.0f);
}

// 1) init: zero degcnt + ovf_cnt; block 0: dtype detect + fused-weight prep
__global__ void k_init(const unsigned int* __restrict__ ei_w,
                       const unsigned int* __restrict__ ea_w,
                       int* __restrict__ flags,
                       unsigned long long* __restrict__ degcnt,
                       int* __restrict__ ovf_cnt,
                       float* __restrict__ consts,
                       const void* czw, const void* czb,
                       const void* chw, const void* chb,
                       const void* lzw, const void* lzb,
                       const void* lhw, const void* lhb,
                       const void* att, const void* ow, const void* ob) {
  int tid = threadIdx.x;
  int i = blockIdx.x * 256 + tid;
  if (i < NN) degcnt[i] = 0ull;
  if (blockIdx.x == 1 && tid == 0) *ovf_cnt = 0;
  if (blockIdx.x != 0) return;

  __shared__ int sfl[2];
  if (tid < 64) {
    // edge_attr in (0,1): packed-bf16 words have sign bits 15/31 == 0; f32 words random bit15
    unsigned long long b1 = __ballot((ea_w[tid] >> 15) & 1u);
    // edge_index < 20000: int64 arrays have all odd 32-bit words == 0
    unsigned long long b2 = __ballot(ei_w[2 * tid + 1] != 0u);
    if (tid == 0) {
      int f0 = (b1 == 0ull) ? 1 : 0;   // 1 = floats are bf16
      int f1 = (b2 == 0ull) ? 1 : 0;   // 1 = indices are int64
      flags[0] = f0; flags[1] = f1; sfl[0] = f0; sfl[1] = f1;
    }
  }
  __syncthreads();
  int isbf = sfl[0];

  // fused gate weights: Wz = conv_z_w @ lin_z_w[:64], Wh = conv_h_w @ lin_h_w[:64]
  for (int idx = tid; idx < 512; idx += 256) {
    int f = idx >> 6, k = idx & 63;
    float sz = 0.f, sh = 0.f;
    for (int h = 0; h < 64; ++h) {
      sz += ldw(czw, f * 64 + h, isbf) * ldw(lzw, h * 64 + k, isbf);
      sh += ldw(chw, f * 64 + h, isbf) * ldw(lhw, h * 64 + k, isbf);
    }
    consts[WZ_O + idx] = sz; consts[WH_O + idx] = sh;
  }
  for (int idx = tid; idx < 64; idx += 256) {
    float sz = ldw(lzb, idx, isbf), sh = ldw(lhb, idx, isbf);
    for (int h = 0; h < 64; ++h) {
      sz += ldw(czb, h, isbf) * ldw(lzw, h * 64 + idx, isbf);
      sh += ldw(chb, h, isbf) * ldw(lhw, h * 64 + idx, isbf);
    }
    consts[BZ_O + idx] = sz; consts[BH_O + idx] = sh;
  }
  // out weights transposed [p][k], row-padded to 68 to break bank alignment
  for (int idx = tid; idx < 816; idx += 256) {
    int p = idx / 68, kk = idx % 68;
    consts[OWT_O + idx] = (kk < 64) ? ldw(ow, kk * 12 + p, isbf) : 0.f;
  }
  if (tid < 12) consts[OB_O + tid] = ldw(ob, tid, isbf);
  if (tid == 0) {
    float a[12]; float m = -1e30f;
    for (int p = 0; p < 12; ++p) { a[p] = ldw(att, p, isbf); m = fmaxf(m, a[p]); }
    float ssum = 0.f;
    for (int p = 0; p < 12; ++p) { a[p] = __expf(a[p] - m); ssum += a[p]; }
    for (int p = 0; p < 12; ++p) consts[PR_O + p] = a[p] / ssum;
  }
}

// 2) single-pass adjacency build: one packed 64-bit atomic per edge gives BOTH the
//    slot index (count, hi32) and the weighted-degree accumulation (fixed point, lo32).
__global__ void k_append(const void* __restrict__ ei, const void* __restrict__ ea,
                         const int* __restrict__ flags,
                         unsigned long long* __restrict__ degcnt,
                         unsigned int* __restrict__ slab,
                         int* __restrict__ ovf_cnt, int* __restrict__ ovf_dst,
                         unsigned int* __restrict__ ovf_pack) {
  int isbf = flags[0], is64 = flags[1];
  int e = blockIdx.x * blockDim.x + threadIdx.x;
  if (e >= EE) return;
  int r, c;
  if (is64) {
    r = (int)((const unsigned int*)ei)[2 * e];
    c = (int)((const unsigned int*)ei)[2 * (EE + e)];
  } else {
    r = ((const int*)ei)[e];
    c = ((const int*)ei)[EE + e];
  }
  unsigned short wb;
  float w;
  if (isbf) { wb = ((const unsigned short*)ea)[e]; w = b2f(wb); }
  else      { w = ((const float*)ea)[e]; wb = f2b(w); }
  unsigned long long pk = (1ull << 32) |
      (unsigned long long)(unsigned int)__float2int_rn(w * 1048576.0f);
  unsigned long long old = atomicAdd(&degcnt[c], pk);
  int pos = (int)(old >> 32);
  unsigned int packed = ((unsigned int)wb << 16) | (unsigned int)r;
  if (pos < CAP) {
    slab[c * CAP + pos] = packed;
  } else {
    int oi = atomicAdd(ovf_cnt, 1);
    if (oi < OVCAP) { ovf_dst[oi] = c; ovf_pack[oi] = packed; }
  }
}

#define ACC8(u, v)                                           \
  { float x0, x1;                                            \
    upk((u).x, x0, x1); a[0] += (v) * x0; a[1] += (v) * x1;  \
    upk((u).y, x0, x1); a[2] += (v) * x0; a[3] += (v) * x1;  \
    upk((u).z, x0, x1); a[4] += (v) * x0; a[5] += (v) * x1;  \
    upk((u).w, x0, x1); a[6] += (v) * x0; a[7] += (v) * x1; }

#define ACCF8(u0, u1, v)                                                       \
  { a[0] += (v) * (u0).x; a[1] += (v) * (u0).y; a[2] += (v) * (u0).z;          \
    a[3] += (v) * (u0).w; a[4] += (v) * (u1).x; a[5] += (v) * (u1).y;          \
    a[6] += (v) * (u1).z; a[7] += (v) * (u1).w; }

// 3) barrier-free wave-per-node: 4 waves/block, each wave owns one node end-to-end.
//    All cross-lane traffic is intra-wave (LDS ops in-order within a wave);
//    the only block barrier is after the shared weight-table staging.
__global__ void __launch_bounds__(256) k_node(
    const void* __restrict__ x,
    const unsigned long long* __restrict__ degcnt,
    const unsigned int* __restrict__ slab,
    const int* __restrict__ ovf_cnt, const int* __restrict__ ovf_dst,
    const unsigned int* __restrict__ ovf_pack,
    const float* __restrict__ consts, const int* __restrict__ flags,
    void* __restrict__ out) {
  __shared__ __align__(16) float sow[840];        // owT 816 | ob 12 | pr 12
  __shared__ __align__(16) int2  sv[4 * SVC];     // per-wave edges {soff, v-bits}
  __shared__ __align__(16) float accT[4 * 384];   // per-wave [b][p][f]
  __shared__ __align__(16) float hw[4 * 272];     // per-wave [b][68]
  __shared__ int swcnt[4];

  const int tid  = threadIdx.x;
  const int w    = tid >> 6;
  const int lane = tid & 63;
  const int isbf = flags[0];
  const int n    = blockIdx.x * 4 + w;

  for (int i = tid; i < 840; i += 256) sow[i] = consts[OWT_O + i];
  float wz[8], wh[8];
#pragma unroll
  for (int f = 0; f < 8; ++f) {
    wz[f] = consts[WZ_O + f * 64 + lane];
    wh[f] = consts[WH_O + f * 64 + lane];
  }
  const float bz = consts[BZ_O + lane], bh = consts[BH_O + lane];

  // --- stage this wave's edges into its LDS slab ---
  unsigned long long dcn = degcnt[n];
  int cnt = (int)(dcn >> 32);
  int base = cnt < CAP ? cnt : CAP;
  const float dn = rsqrtf(degf(dcn) + 1.0f);
  int2* svw = &sv[w * SVC];
  if (lane == 0) swcnt[w] = base;
  if (lane < base) {
    unsigned int pk = slab[n * CAP + lane];
    int s = (int)(pk & 0xffffu);
    float v = b2f((unsigned short)(pk >> 16)) * rsqrtf(degf(degcnt[s]) + 1.0f);
    svw[lane] = make_int2(s * 96, __float_as_int(v));
  }
  int m0 = base;
  {
    int ov = ovf_cnt[0];                 // expected 0
    if (ov > 0) {
      if (ov > OVCAP) ov = OVCAP;
      for (int i = lane; i < ov; i += 64) {
        if (ovf_dst[i] == n) {
          int idx = atomicAdd(&swcnt[w], 1);
          if (idx < SVC - 1) {
            unsigned int pk = ovf_pack[i];
            int s = (int)(pk & 0xffffu);
            float v = b2f((unsigned short)(pk >> 16)) * rsqrtf(degf(degcnt[s]) + 1.0f);
            svw[idx] = make_int2(s * 96, __float_as_int(v));
          }
        }
      }
      __builtin_amdgcn_wave_barrier();
      m0 = swcnt[w];
      if (m0 > SVC - 1) m0 = SVC - 1;
    }
  }
  if (lane == 0) svw[m0] = make_int2(n * 96, __float_as_int(dn));  // self loop
  const int m1 = m0 + 1;
  __syncthreads();   // sow ready (cross-wave); svw writes also drained

  // --- gather: lanes 0..47, lane owns 8 payload elems; 2-wide pipelined loads ---
  float a[8];
#pragma unroll
  for (int t = 0; t < 8; ++t) a[t] = 0.f;
  if (lane < 48) {
    const long xbase = (long)(lane / 12) * (NN * 96) + 8 * (lane % 12);
    if (isbf) {
      const unsigned short* xb = (const unsigned short*)x;
      int j = 0;
      for (; j + 1 < m1; j += 2) {
        int2 e0 = svw[j], e1 = svw[j + 1];
        uint4 u0 = *(const uint4*)(xb + xbase + e0.x);
        uint4 u1 = *(const uint4*)(xb + xbase + e1.x);
        float v0 = __int_as_float(e0.y), v1 = __int_as_float(e1.y);
        ACC8(u0, v0); ACC8(u1, v1);
      }
      if (j < m1) {
        int2 e0 = svw[j];
        uint4 u0 = *(const uint4*)(xb + xbase + e0.x);
        float v0 = __int_as_float(e0.y);
        ACC8(u0, v0);
      }
    } else {
      const float* xf = (const float*)x;
      int j = 0;
      for (; j + 1 < m1; j += 2) {
        int2 e0 = svw[j], e1 = svw[j + 1];
        const float4* p0 = (const float4*)(xf + xbase + e0.x);
        const float4* p1 = (const float4*)(xf + xbase + e1.x);
        float4 u00 = p0[0], u01 = p0[1], u10 = p1[0], u11 = p1[1];
        float v0 = __int_as_float(e0.y), v1 = __int_as_float(e1.y);
        ACCF8(u00, u01, v0); ACCF8(u10, u11, v1);
      }
      if (j < m1) {
        int2 e0 = svw[j];
        const float4* p0 = (const float4*)(xf + xbase + e0.x);
        float4 u00 = p0[0], u01 = p0[1];
        float v0 = __int_as_float(e0.y);
        ACCF8(u00, u01, v0);
      }
    }
    // scatter-transpose into accT[b][p][f], scaled by dn
    float* accTw = &accT[w * 384];
    const int bq = (lane / 12) * 96, oc = 8 * (lane % 12);
#pragma unroll
    for (int t = 0; t < 8; ++t) {
      int eib = oc + t;
      int f = eib / 12, p = eib % 12;
      accTw[bq + p * 8 + f] = dn * a[t];
    }
  }
  __builtin_amdgcn_wave_barrier();

  // --- gates: lane = hidden index k; all 48 (b,p) pairs; h accumulated per b ---
  {
    const float* accTw = &accT[w * 384];
    float* hww = &hw[w * 272];
#pragma unroll
    for (int b = 0; b < 4; ++b) {
      float hbl = 0.f;
#pragma unroll
      for (int p = 0; p < 12; ++p) {
        const float4* A = (const float4*)&accTw[b * 96 + p * 8];
        float4 A0 = A[0], A1 = A[1];
        float za = bz + A0.x * wz[0] + A0.y * wz[1] + A0.z * wz[2] + A0.w * wz[3]
                      + A1.x * wz[4] + A1.y * wz[5] + A1.z * wz[6] + A1.w * wz[7];
        float ta = bh + A0.x * wh[0] + A0.y * wh[1] + A0.z * wh[2] + A0.w * wh[3]
                      + A1.x * wh[4] + A1.y * wh[5] + A1.z * wh[6] + A1.w * wh[7];
        // (1 - sigmoid(za)) * tanh(ta) = (eh-1) / ((1+ea)(1+eh)), ea=e^za, eh=e^{2ta}
        float ea = __expf(za);
        float eh = __expf(2.0f * fminf(ta, 40.0f));
        hbl += sow[828 + p] * (eh - 1.0f) *
               __builtin_amdgcn_rcpf((1.0f + ea) * (1.0f + eh));
      }
      hww[b * 68 + lane] = fmaxf(hbl, 0.f);   // relu
    }
  }
  __builtin_amdgcn_wave_barrier();

  // --- out projection: lane t<48 -> (b,p); vectorized b128 reads ---
  if (lane < 48) {
    const float* hww = &hw[w * 272];
    int b = lane / 12, p = lane % 12;
    float o = sow[816 + p];
#pragma unroll
    for (int kq = 0; kq < 16; ++kq) {
      float4 hv = *(const float4*)&hww[b * 68 + 4 * kq];
      float4 wv = *(const float4*)&sow[p * 68 + 4 * kq];
      o += hv.x * wv.x + hv.y * wv.y + hv.z * wv.z + hv.w * wv.w;
    }
    int oi = (b * NN + n) * 12 + p;
    if (isbf) ((unsigned short*)out)[oi] = f2b(o);
    else      ((float*)out)[oi] = o;
  }
}

extern "C" void kernel_launch(void* const* d_in, const int* in_sizes, int n_in,
                              void* d_out, int out_size, void* d_ws, size_t ws_size,
                              hipStream_t stream) {
  const void* x   = d_in[0];
  const void* ei  = d_in[1];
  const void* ea  = d_in[2];
  const void* czw = d_in[3];
  const void* czb = d_in[4];
  // d_in[5], d_in[6]: conv_r_* — dead (H0 = 0)
  const void* chw = d_in[7];
  const void* chb = d_in[8];
  const void* lzw = d_in[9];
  const void* lzb = d_in[10];
  // d_in[11], d_in[12]: lin_r_* — dead
  const void* lhw = d_in[13];
  const void* lhb = d_in[14];
  const void* att = d_in[15];
  const void* ow  = d_in[16];
  const void* ob  = d_in[17];

  // workspace ~5.4 MB
  char* ws = (char*)d_ws;
  int*   flags   = (int*)  (ws + 0);
  float* consts  = (float*)(ws + 256);          // 1992 f32 -> ends 8224
  unsigned long long* degcnt = (unsigned long long*)(ws + 8448);   // 160000 -> 168448
  int*   ovf_cnt = (int*)  (ws + 168448);
  int*   ovf_dst = (int*)  (ws + 168704);       // 32768 -> 201472
  unsigned int* ovf_pack = (unsigned int*)(ws + 201472);  // 32768 -> 234240
  unsigned int* slab     = (unsigned int*)(ws + 240000);  // 5,120,000 -> 5,360,000

  k_init<<<dim3(79), dim3(256), 0, stream>>>((const unsigned int*)ei,
                                             (const unsigned int*)ea, flags, degcnt,
                                             ovf_cnt, consts, czw, czb, chw, chb,
                                             lzw, lzb, lhw, lhb, att, ow, ob);
  k_append<<<dim3(1250), dim3(256), 0, stream>>>(ei, ea, flags, degcnt, slab,
                                                 ovf_cnt, ovf_dst, ovf_pack);
  k_node<<<dim3(NN / 4), dim3(256), 0, stream>>>(x, degcnt, slab, ovf_cnt, ovf_dst,
                                                 ovf_pack, consts, flags, d_out);
}